// Round 1
// baseline (117.537 us; speedup 1.0000x reference)
//
#include <hip/hip_runtime.h>
#include <math.h>

// Problem constants (from reference)
#define BB   32
#define HH   112
#define WW   112
#define AA   9
#define NBOX 24
#define NBOXES (BB*NBOX)            // 768
#define NCELLS (BB*HH*WW*AA)        // 3,612,672
#define NFLOATS (NCELLS*5)          // 18,063,360
#define NF4 (NFLOATS/4)             // 4,515,840

__device__ __forceinline__ float softplusf(float x) {
    // stable: log(1+e^x) = max(x,0) + log1p(exp(-|x|))
    return fmaxf(x, 0.0f) + log1pf(expf(-fabsf(x)));
}

// Kernel A: dense sum of softplus(predictions[...,4]) over all cells.
// Vectorized float4 reads of the whole tensor (we have to fetch every line
// anyway at stride 20B); each float4 contains 0 or 1 obj element.
__global__ __launch_bounds__(256) void softplus_sum_kernel(
        const float4* __restrict__ pred4, double* __restrict__ partials) {
    const int tid = blockIdx.x * blockDim.x + threadIdx.x;
    const int stride = gridDim.x * blockDim.x;
    double acc = 0.0;
    for (int i = tid; i < NF4; i += stride) {
        float4 v = pred4[i];
        unsigned i4 = (unsigned)i * 4u;
        unsigned r = i4 % 5u;          // element (i4 + (4-r)) is the obj slot
        if (r != 0u) {
            unsigned j = 4u - r;       // in 0..3
            float x = (j == 0) ? v.x : (j == 1) ? v.y : (j == 2) ? v.z : v.w;
            acc += (double)softplusf(x);
        }
    }
    __shared__ double sm[256];
    sm[threadIdx.x] = acc;
    __syncthreads();
    for (int s = 128; s > 0; s >>= 1) {
        if (threadIdx.x < s) sm[threadIdx.x] += sm[threadIdx.x + s];
        __syncthreads();
    }
    if (threadIdx.x == 0) partials[blockIdx.x] = sm[0];
}

// Kernel B: everything sparse. One block, 1024 threads.
// Threads 0..767 each own one (batch, box). Build targets in LDS, resolve
// duplicate (cell,anchor) keys with last-write-wins (largest box index),
// gather predictions at winner cells, reduce, finalize 5 outputs.
__global__ __launch_bounds__(1024) void yolo_sparse_kernel(
        const float* __restrict__ pred, const float* __restrict__ bboxes,
        const double* __restrict__ partials, int npart,
        float* __restrict__ out) {
    const int t = threadIdx.x;

    __shared__ int           s_key[NBOXES];
    __shared__ unsigned char s_val[NBOXES];
    __shared__ float         s_tv[NBOXES][4];
    __shared__ double r_c[1024], r_o[1024], r_n[1024], r_s[1024];
    __shared__ int    r_cnt[1024];

    // ---- phase 1: per-box target computation ----
    if (t < NBOXES) {
        const float* bb = bboxes + t * 4;
        float cx = bb[0], cy = bb[1], w = bb[2], h = bb[3];
        bool valid = (cx != 0.0f) || (cy != 0.0f) || (w != 0.0f) || (h != 0.0f);

        int gx = (int)floorf(cx * (float)WW);
        gx = min(max(gx, 0), WW - 1);
        int gy = (int)floorf(cy * (float)HH);
        gy = min(max(gy, 0), HH - 1);

        // anchors: for s in {32,64,128}, for r in {0.5,1,2}: (s*sqrt(r)/224, s/sqrt(r)/224)
        // computed in double then cast to f32 to match the Python-f64 -> f32 path
        float best_iou = -1.0f;
        int best = 0;
        float aw_b = 1.0f, ah_b = 1.0f;
        const double ss[3] = {32.0, 64.0, 128.0};
        const double rr[3] = {0.5, 1.0, 2.0};
        #pragma unroll
        for (int i = 0; i < 3; ++i) {
            #pragma unroll
            for (int j = 0; j < 3; ++j) {
                float aw = (float)(ss[i] * sqrt(rr[j]) / 224.0);
                float ah = (float)(ss[i] / sqrt(rr[j]) / 224.0);
                float inter = fminf(w, aw) * fminf(h, ah);
                float uni = w * h + aw * ah - inter;
                float iou = inter / (uni + 1e-16f);
                if (iou > best_iou) { best_iou = iou; best = i * 3 + j; aw_b = aw; ah_b = ah; }
            }
        }
        s_key[t] = (gy * WW + gx) * AA + best;
        s_val[t] = valid ? 1 : 0;
        s_tv[t][0] = cx * (float)WW - (float)gx;
        s_tv[t][1] = cy * (float)HH - (float)gy;
        s_tv[t][2] = logf(w / aw_b + 1e-16f);
        s_tv[t][3] = logf(h / ah_b + 1e-16f);
    }
    __syncthreads();

    // ---- phase 2: winner resolution + gather ----
    double csum = 0.0, osum = 0.0, nsub = 0.0;
    int cnt = 0;
    if (t < NBOXES && s_val[t]) {
        const int batch = t / NBOX;
        const int bend = (batch + 1) * NBOX;
        const int mykey = s_key[t];
        bool winner = true;
        for (int m = t + 1; m < bend; ++m) {
            if (s_val[m] && s_key[m] == mykey) { winner = false; break; }
        }
        if (winner) {
            const size_t cell = (size_t)batch * (HH * WW * AA) + (size_t)mykey;
            const float* p = pred + cell * 5;
            float d0 = p[0] - s_tv[t][0];
            float d1 = p[1] - s_tv[t][1];
            float d2 = p[2] - s_tv[t][2];
            float d3 = p[3] - s_tv[t][3];
            csum = (double)d0 * d0 + (double)d1 * d1 + (double)d2 * d2 + (double)d3 * d3;
            float op = p[4];
            osum = (double)softplusf(-op);
            nsub = (double)softplusf(op);
            cnt = 1;
        }
    }

    // fold in dense partials
    double psum = 0.0;
    for (int i = t; i < npart; i += 1024) psum += partials[i];

    r_c[t] = csum; r_o[t] = osum; r_n[t] = nsub; r_s[t] = psum; r_cnt[t] = cnt;
    __syncthreads();
    for (int s = 512; s > 0; s >>= 1) {
        if (t < s) {
            r_c[t] += r_c[t + s];
            r_o[t] += r_o[t + s];
            r_n[t] += r_n[t + s];
            r_s[t] += r_s[t + s];
            r_cnt[t] += r_cnt[t + s];
        }
        __syncthreads();
    }

    if (t == 0) {
        double S = r_s[0];
        int n_pos = r_cnt[0];
        double denom_pos = fmax((double)n_pos, 1.0);
        double denom_neg = fmax((double)NCELLS - (double)n_pos, 1.0);
        float coord = (float)(5.0 * r_c[0] / denom_pos);
        float obj   = (float)(r_o[0] / denom_pos);
        float noobj = (float)(0.5 * (S - r_n[0]) / denom_neg);
        float total = coord + obj + noobj;
        out[0] = total;
        out[1] = coord;
        out[2] = obj;
        out[3] = noobj;
        out[4] = 0.0f;
    }
}

extern "C" void kernel_launch(void* const* d_in, const int* in_sizes, int n_in,
                              void* d_out, int out_size, void* d_ws, size_t ws_size,
                              hipStream_t stream) {
    const float* pred   = (const float*)d_in[0];
    const float* bboxes = (const float*)d_in[1];
    double* partials = (double*)d_ws;

    size_t maxp = ws_size / sizeof(double);
    int npart = (int)(maxp < 1024 ? maxp : 1024);
    if (npart < 1) npart = 1;

    hipLaunchKernelGGL(softplus_sum_kernel, dim3(npart), dim3(256), 0, stream,
                       (const float4*)pred, partials);
    hipLaunchKernelGGL(yolo_sparse_kernel, dim3(1), dim3(1024), 0, stream,
                       pred, bboxes, partials, npart, (float*)d_out);
}

// Round 2
// 111.238 us; speedup vs baseline: 1.0566x; 1.0566x over previous
//
#include <hip/hip_runtime.h>
#include <math.h>

// Problem constants (from reference)
#define BB   32
#define HH   112
#define WW   112
#define AA   9
#define NBOX 24
#define NBOXES (BB*NBOX)            // 768
#define NCELLS (BB*HH*WW*AA)        // 3,612,672
#define BLK_A 256
#define NTHREADS_A (NCELLS/4)       // 903,168 (each thread: 4 cells = 20 floats)
#define GRID_A (NTHREADS_A/BLK_A)   // 3528 exactly

__device__ __forceinline__ float softplusf(float x) {
    // stable: log(1+e^x) = max(x,0) + log1p(exp(-|x|))
    return fmaxf(x, 0.0f) + log1pf(expf(-fabsf(x)));
}

// Kernel A: dense sum of softplus(predictions[...,4]) over all cells.
// Branch-free: each thread owns 4 consecutive cells (20 floats = 80 B).
// obj elements sit at float offsets 20t+{4,9,14,19} = float4 indices
// 5t+{1,2,3,4}, lanes {x,y,z,w}. The skipped first 16 B of each 80 B group
// can never cover a whole 64 B line, so every HBM line is still fetched —
// traffic is the mandatory 72.3 MB either way.
__global__ __launch_bounds__(BLK_A) void softplus_sum_kernel(
        const float4* __restrict__ pred4, double* __restrict__ partials) {
    const int tid = blockIdx.x * BLK_A + threadIdx.x;   // < 903,168
    const float4* p = pred4 + (size_t)tid * 5;
    float4 a = p[1];
    float4 b = p[2];
    float4 c = p[3];
    float4 d = p[4];
    double acc = (double)softplusf(a.x) + (double)softplusf(b.y)
               + (double)softplusf(c.z) + (double)softplusf(d.w);

    __shared__ double sm[BLK_A];
    sm[threadIdx.x] = acc;
    __syncthreads();
    for (int s = BLK_A / 2; s > 0; s >>= 1) {
        if (threadIdx.x < s) sm[threadIdx.x] += sm[threadIdx.x + s];
        __syncthreads();
    }
    if (threadIdx.x == 0) partials[blockIdx.x] = sm[0];
}

// Kernel B: everything sparse. One block, 1024 threads.
// Threads 0..767 each own one (batch, box). Build targets in LDS, resolve
// duplicate (cell,anchor) keys with last-write-wins (largest box index),
// gather predictions at winner cells, reduce, finalize 5 outputs.
__global__ __launch_bounds__(1024) void yolo_sparse_kernel(
        const float* __restrict__ pred, const float* __restrict__ bboxes,
        const double* __restrict__ partials, int npart,
        float* __restrict__ out) {
    const int t = threadIdx.x;

    __shared__ int           s_key[NBOXES];
    __shared__ unsigned char s_val[NBOXES];
    __shared__ float         s_tv[NBOXES][4];
    __shared__ double r_c[1024], r_o[1024], r_n[1024], r_s[1024];
    __shared__ int    r_cnt[1024];

    // ---- phase 1: per-box target computation ----
    if (t < NBOXES) {
        const float* bb = bboxes + t * 4;
        float cx = bb[0], cy = bb[1], w = bb[2], h = bb[3];
        bool valid = (cx != 0.0f) || (cy != 0.0f) || (w != 0.0f) || (h != 0.0f);

        int gx = (int)floorf(cx * (float)WW);
        gx = min(max(gx, 0), WW - 1);
        int gy = (int)floorf(cy * (float)HH);
        gy = min(max(gy, 0), HH - 1);

        // anchors: for s in {32,64,128}, for r in {0.5,1,2}:
        //   (s*sqrt(r)/224, s/sqrt(r)/224), computed in f64 then cast to f32
        float best_iou = -1.0f;
        int best = 0;
        float aw_b = 1.0f, ah_b = 1.0f;
        const double ss[3] = {32.0, 64.0, 128.0};
        const double rr[3] = {0.5, 1.0, 2.0};
        #pragma unroll
        for (int i = 0; i < 3; ++i) {
            #pragma unroll
            for (int j = 0; j < 3; ++j) {
                float aw = (float)(ss[i] * sqrt(rr[j]) / 224.0);
                float ah = (float)(ss[i] / sqrt(rr[j]) / 224.0);
                float inter = fminf(w, aw) * fminf(h, ah);
                float uni = w * h + aw * ah - inter;
                float iou = inter / (uni + 1e-16f);
                if (iou > best_iou) { best_iou = iou; best = i * 3 + j; aw_b = aw; ah_b = ah; }
            }
        }
        s_key[t] = (gy * WW + gx) * AA + best;
        s_val[t] = valid ? 1 : 0;
        s_tv[t][0] = cx * (float)WW - (float)gx;
        s_tv[t][1] = cy * (float)HH - (float)gy;
        s_tv[t][2] = logf(w / aw_b + 1e-16f);
        s_tv[t][3] = logf(h / ah_b + 1e-16f);
    }
    __syncthreads();

    // ---- phase 2: winner resolution + gather ----
    double csum = 0.0, osum = 0.0, nsub = 0.0;
    int cnt = 0;
    if (t < NBOXES && s_val[t]) {
        const int batch = t / NBOX;
        const int bend = (batch + 1) * NBOX;
        const int mykey = s_key[t];
        bool winner = true;
        for (int m = t + 1; m < bend; ++m) {
            if (s_val[m] && s_key[m] == mykey) { winner = false; break; }
        }
        if (winner) {
            const size_t cell = (size_t)batch * (HH * WW * AA) + (size_t)mykey;
            const float* p = pred + cell * 5;
            float d0 = p[0] - s_tv[t][0];
            float d1 = p[1] - s_tv[t][1];
            float d2 = p[2] - s_tv[t][2];
            float d3 = p[3] - s_tv[t][3];
            csum = (double)d0 * d0 + (double)d1 * d1 + (double)d2 * d2 + (double)d3 * d3;
            float op = p[4];
            osum = (double)softplusf(-op);
            nsub = (double)softplusf(op);
            cnt = 1;
        }
    }

    // fold in dense partials
    double psum = 0.0;
    for (int i = t; i < npart; i += 1024) psum += partials[i];

    r_c[t] = csum; r_o[t] = osum; r_n[t] = nsub; r_s[t] = psum; r_cnt[t] = cnt;
    __syncthreads();
    for (int s = 512; s > 0; s >>= 1) {
        if (t < s) {
            r_c[t] += r_c[t + s];
            r_o[t] += r_o[t + s];
            r_n[t] += r_n[t + s];
            r_s[t] += r_s[t + s];
            r_cnt[t] += r_cnt[t + s];
        }
        __syncthreads();
    }

    if (t == 0) {
        double S = r_s[0];
        int n_pos = r_cnt[0];
        double denom_pos = fmax((double)n_pos, 1.0);
        double denom_neg = fmax((double)NCELLS - (double)n_pos, 1.0);
        float coord = (float)(5.0 * r_c[0] / denom_pos);
        float obj   = (float)(r_o[0] / denom_pos);
        float noobj = (float)(0.5 * (S - r_n[0]) / denom_neg);
        float total = coord + obj + noobj;
        out[0] = total;
        out[1] = coord;
        out[2] = obj;
        out[3] = noobj;
        out[4] = 0.0f;
    }
}

extern "C" void kernel_launch(void* const* d_in, const int* in_sizes, int n_in,
                              void* d_out, int out_size, void* d_ws, size_t ws_size,
                              hipStream_t stream) {
    const float* pred   = (const float*)d_in[0];
    const float* bboxes = (const float*)d_in[1];
    double* partials = (double*)d_ws;   // needs 3528*8 = 28 KB; ws is much larger

    hipLaunchKernelGGL(softplus_sum_kernel, dim3(GRID_A), dim3(BLK_A), 0, stream,
                       (const float4*)pred, partials);
    hipLaunchKernelGGL(yolo_sparse_kernel, dim3(1), dim3(1024), 0, stream,
                       pred, bboxes, partials, GRID_A, (float*)d_out);
}